// Round 1
// baseline (388.456 us; speedup 1.0000x reference)
//
#include <hip/hip_runtime.h>

typedef short short8 __attribute__((ext_vector_type(8)));
typedef float float4v __attribute__((ext_vector_type(4)));

__device__ __forceinline__ unsigned short f2bf(float f) {
  unsigned int u = __builtin_bit_cast(unsigned int, f);
  u += 0x7FFFu + ((u >> 16) & 1u);   // round-to-nearest-even
  return (unsigned short)(u >> 16);
}

// x (B,C,T) f32 -> xb bf16 with +1 time shift (xshift[t] = x[t+1], 0 at t=T-1)
__global__ void cvt_shift_x(const float* __restrict__ x, unsigned short* __restrict__ xb, int n) {
  int i = blockIdx.x * 256 + threadIdx.x;
  if (i >= n) return;
  int t = i & 4095;
  float v = (t == 4095) ? 0.f : x[i + 1];
  xb[i] = f2bf(v);
}

__global__ void cvt_plain(const float* __restrict__ s, unsigned short* __restrict__ d, int n) {
  int i = blockIdx.x * 256 + threadIdx.x;
  if (i >= n) return;
  d[i] = f2bf(s[i]);
}

// src (K,512) f32 row-major -> dst (512,K) bf16 row-major (B-operand layout)
__global__ void transpose_w(const float* __restrict__ src, unsigned short* __restrict__ dst, int K) {
  int i = blockIdx.x * 256 + threadIdx.x;
  if (i >= K * 512) return;
  int n = i & 511, k = i >> 9;
  dst[n * K + k] = f2bf(src[i]);
}

// Unified GEMM: C[r,n] = act(biasv[n] + sum_k A[base(r)+k] * Bt[n*K + k])
// base(r) = (r + (r/RPB)*EXTRA) * BSCALE   (window-view convs + batched matmul)
// Bt may be per-batch (bStrideB). Normal store: out[r*512+n] (f32 or bf16, +addm).
// TRANS store: out[bb*outBatchStride + (n0+f)*outLd + t_local]  (bf16, via LDS repack)
template<int BM, int BN, bool RELU, bool OBF16, bool TRANS, bool ADDM>
__global__ __launch_bounds__(256)
void gemm_bt(const unsigned short* __restrict__ A,
             const unsigned short* __restrict__ Bt,
             const float* __restrict__ biasv,
             const float* __restrict__ addm,
             void* __restrict__ outp,
             int M, int K, int RPB, int EXTRA, int BSCALE,
             long long bStrideB, long long outBatchStride, int outLd)
{
  constexpr int WM = BM / 2, WN = BN / 2;
  constexpr int NI = WM / 16, NJ = WN / 16;
  constexpr int ACH = (BM * 32) / (256 * 8);   // 8-element chunks per thread (A)
  constexpr int BCH = (BN * 32) / (256 * 8);
  constexpr int SA = BM * 40, SB = BN * 40;    // stride 40: <=2-way bank conflicts (free)
  constexpr int SMEMN = TRANS ? ((128 * 136 > SA + SB) ? 128 * 136 : SA + SB) : (SA + SB);
  __shared__ unsigned short smem[SMEMN];
  unsigned short* sA = smem;
  unsigned short* sB = smem + SA;

  const int tid  = threadIdx.x;
  const int lane = tid & 63;
  const int wave = tid >> 6;
  const int wm = wave >> 1, wn = wave & 1;
  const int lr = lane & 15, quad = lane >> 4;

  const int r0 = blockIdx.x * BM;
  const int n0 = blockIdx.y * BN;
  const int bb = r0 / RPB;
  const long long bOffB = (long long)bb * bStrideB;

  long long aBase[ACH]; int aLds[ACH];
#pragma unroll
  for (int c = 0; c < ACH; ++c) {
    int idx = c * 256 + tid;
    int row = idx >> 2, seg = idx & 3;
    int r = r0 + row; if (r > M - 1) r = M - 1;          // clamp partial tiles
    aBase[c] = ((long long)r + (long long)(r / RPB) * EXTRA) * BSCALE + seg * 8;
    aLds[c] = row * 40 + seg * 8;
  }
  long long bBase[BCH]; int bLds[BCH];
#pragma unroll
  for (int c = 0; c < BCH; ++c) {
    int idx = c * 256 + tid;
    int row = idx >> 2, seg = idx & 3;
    bBase[c] = (long long)(n0 + row) * K + bOffB + seg * 8;
    bLds[c] = row * 40 + seg * 8;
  }

  float4v acc[NI][NJ];
  const float4v z4 = {0.f, 0.f, 0.f, 0.f};
#pragma unroll
  for (int i = 0; i < NI; ++i)
#pragma unroll
    for (int j = 0; j < NJ; ++j) acc[i][j] = z4;

  const int aoff0 = (wm * WM + lr) * 40 + quad * 8;
  const int boff0 = (wn * WN + lr) * 40 + quad * 8;

  for (int k0 = 0; k0 < K; k0 += 32) {
#pragma unroll
    for (int c = 0; c < ACH; ++c)
      *(uint4*)(sA + aLds[c]) = *(const uint4*)(A + aBase[c] + k0);
#pragma unroll
    for (int c = 0; c < BCH; ++c)
      *(uint4*)(sB + bLds[c]) = *(const uint4*)(Bt + bBase[c] + k0);
    __syncthreads();
    short8 af[NI], bfg[NJ];
#pragma unroll
    for (int i = 0; i < NI; ++i) af[i] = *(const short8*)(sA + aoff0 + i * 16 * 40);
#pragma unroll
    for (int j = 0; j < NJ; ++j) bfg[j] = *(const short8*)(sB + boff0 + j * 16 * 40);
#pragma unroll
    for (int i = 0; i < NI; ++i)
#pragma unroll
      for (int j = 0; j < NJ; ++j)
        acc[i][j] = __builtin_amdgcn_mfma_f32_16x16x32_bf16(af[i], bfg[j], acc[i][j], 0, 0, 0);
    __syncthreads();
  }

  if (TRANS) {
    // repack D (t,f) -> LDS (f-major, stride 136: 16B-aligned rows, 2-way conflicts)
    unsigned short* Ts = smem;
#pragma unroll
    for (int j = 0; j < NJ; ++j) {
      int fr = wn * WN + j * 16 + lr;
      float bv = biasv[n0 + fr];
#pragma unroll
      for (int i = 0; i < NI; ++i) {
        int tr = wm * WM + i * 16 + quad * 4;
        unsigned long long pk = 0;
#pragma unroll
        for (int g = 0; g < 4; ++g)
          pk |= (unsigned long long)f2bf(acc[i][j][g] + bv) << (16 * g);
        *(unsigned long long*)(Ts + fr * 136 + tr) = pk;
      }
    }
    __syncthreads();
    int fr = tid >> 1, sg = tid & 1;
    int t0l = r0 - bb * RPB;
    unsigned short* dst = (unsigned short*)outp + (long long)bb * outBatchStride
                        + (long long)(n0 + fr) * outLd + t0l + sg * 64;
    const unsigned short* srcp = Ts + fr * 136 + sg * 64;
#pragma unroll
    for (int u = 0; u < 8; ++u)
      *(uint4*)(dst + u * 8) = *(const uint4*)(srcp + u * 8);
  } else {
#pragma unroll
    for (int j = 0; j < NJ; ++j) {
      int n_g = n0 + wn * WN + j * 16 + lr;
      float bv = biasv ? biasv[n_g] : 0.f;
#pragma unroll
      for (int i = 0; i < NI; ++i) {
        int r_base = r0 + wm * WM + i * 16 + quad * 4;
#pragma unroll
        for (int g = 0; g < 4; ++g) {
          int r_g = r_base + g;
          if (r_g >= M) continue;
          float v = acc[i][j][g] + bv;
          if (RELU) v = fmaxf(v, 0.f);
          long long oidx = (long long)r_g * 512 + n_g;
          if (ADDM) v += addm[oidx];
          if (OBF16) ((unsigned short*)outp)[oidx] = f2bf(v);
          else       ((float*)outp)[oidx] = v;
        }
      }
    }
  }
}

extern "C" void kernel_launch(void* const* d_in, const int* in_sizes, int n_in,
                              void* d_out, int out_size, void* d_ws, size_t ws_size,
                              hipStream_t stream) {
  const float* x   = (const float*)d_in[0];
  const float* z   = (const float*)d_in[1];
  const float* ww1 = (const float*)d_in[2];
  const float* wb1 = (const float*)d_in[3];
  const float* ww2 = (const float*)d_in[4];
  const float* wb2 = (const float*)d_in[5];
  const float* bw1 = (const float*)d_in[6];
  const float* bb1 = (const float*)d_in[7];
  const float* bw2 = (const float*)d_in[8];
  const float* bb2 = (const float*)d_in[9];

  char* ws = (char*)d_ws;
  unsigned short* xb  = (unsigned short*)ws; ws += 16777216ll * 2;  // (8,512,4096) shifted bf16
  unsigned short* zb  = (unsigned short*)ws; ws += 4196352ll  * 2;  // (8,4098,128) bf16
  unsigned short* h1w = (unsigned short*)ws; ws += 16781312ll * 2;  // (8,4097,512) bf16
  unsigned short* wT  = (unsigned short*)ws; ws += 16777216ll * 2;  // (8,512,4096) WtT bf16
  unsigned short* h1b = (unsigned short*)ws; ws += 2101248ll  * 2;  // (8,513,512) bf16
  float*          bM  = (float*)ws;          ws += 2097152ll  * 4;  // (8,512,512) f32
  unsigned short* w1T = (unsigned short*)ws; ws += 131072ll * 2;    // (512,256)
  unsigned short* w2T = (unsigned short*)ws; ws += 524288ll * 2;    // (512,1024)
  unsigned short* b1T = (unsigned short*)ws; ws += 131072ll * 2;
  unsigned short* b2T = (unsigned short*)ws; ws += 524288ll * 2;

  transpose_w<<<(256 * 512) / 256, 256, 0, stream>>>(ww1, w1T, 256);
  transpose_w<<<(1024 * 512) / 256, 256, 0, stream>>>(ww2, w2T, 1024);
  transpose_w<<<(256 * 512) / 256, 256, 0, stream>>>(bw1, b1T, 256);
  transpose_w<<<(1024 * 512) / 256, 256, 0, stream>>>(bw2, b2T, 1024);
  cvt_plain<<<(4196352 + 255) / 256, 256, 0, stream>>>(z, zb, 4196352);
  cvt_shift_x<<<(16777216 + 255) / 256, 256, 0, stream>>>(x, xb, 16777216);

  // conv1-w: h1w = relu(z * w1 + wb1), M=8*4097, K=256, base=(r + b)*128
  gemm_bt<128, 128, true, true, false, false><<<dim3(257, 4), 256, 0, stream>>>(
      zb, w1T, wb1, nullptr, h1w, 32776, 256, 4097, 1, 128, 0, 0, 512);
  // conv1-b (truncated t<513): M=8*513, base=(r + 3585*b)*128
  gemm_bt<64, 128, true, true, false, false><<<dim3(65, 4), 256, 0, stream>>>(
      zb, b1T, bb1, nullptr, h1b, 4104, 256, 513, 3585, 128, 0, 0, 512);
  // conv2-w -> WtT (transposed store): M=8*4096, K=1024, base=(r + b)*512
  gemm_bt<128, 128, false, true, true, false><<<dim3(256, 4), 256, 0, stream>>>(
      h1w, w2T, wb2, nullptr, wT, 32768, 1024, 4096, 1, 512, 0, 512ll * 4096, 4096);
  // conv2-b -> biasM f32: M=8*512, base=(r + b)*512
  gemm_bt<64, 128, false, false, false, false><<<dim3(64, 4), 256, 0, stream>>>(
      h1b, b2T, bb2, nullptr, bM, 4096, 1024, 512, 1, 512, 0, 0, 512);
  // main: out = xshift @ W + biasM, per-batch B (bStrideB), M=8*512, K=4096
  gemm_bt<64, 128, false, false, false, true><<<dim3(64, 4), 256, 0, stream>>>(
      xb, wT, nullptr, bM, d_out, 4096, 4096, 512, 0, 4096, 512ll * 4096, 0, 512);
}

// Round 2
// 374.188 us; speedup vs baseline: 1.0381x; 1.0381x over previous
//
#include <hip/hip_runtime.h>

typedef short short8 __attribute__((ext_vector_type(8)));
typedef float float4v __attribute__((ext_vector_type(4)));
typedef __attribute__((address_space(1))) const unsigned int gu32;
typedef __attribute__((address_space(3))) unsigned int lu32;

__device__ __forceinline__ unsigned short f2bf(float f) {
  unsigned int u = __builtin_bit_cast(unsigned int, f);
  u += 0x7FFFu + ((u >> 16) & 1u);   // round-to-nearest-even
  return (unsigned short)(u >> 16);
}

// x (B,C,T) f32 -> xb bf16 with +1 time shift (xshift[t] = x[t+1], 0 at t=T-1)
__global__ void cvt_shift_x(const float* __restrict__ x, unsigned short* __restrict__ xb, int n) {
  int i = blockIdx.x * 256 + threadIdx.x;
  if (i >= n) return;
  int t = i & 4095;
  float v = (t == 4095) ? 0.f : x[i + 1];
  xb[i] = f2bf(v);
}

__global__ void cvt_plain(const float* __restrict__ s, unsigned short* __restrict__ d, int n) {
  int i = blockIdx.x * 256 + threadIdx.x;
  if (i >= n) return;
  d[i] = f2bf(s[i]);
}

// src (K,512) f32 row-major -> dst (512,K) bf16 row-major (B-operand layout)
__global__ void transpose_w(const float* __restrict__ src, unsigned short* __restrict__ dst, int K) {
  int i = blockIdx.x * 256 + threadIdx.x;
  if (i >= K * 512) return;
  int n = i & 511, k = i >> 9;
  dst[n * K + k] = f2bf(src[i]);
}

// out = bM + sum of 4 split-K partials (all f32, flat 8*512*512 elems)
__global__ void reduce_out(const float4v* __restrict__ p, const float4v* __restrict__ bM,
                           float4v* __restrict__ out) {
  int i = blockIdx.x * 256 + threadIdx.x;
  const int S = 2097152 / 4;
  float4v v = bM[i];
  v += p[i];
  v += p[i + S];
  v += p[i + 2 * S];
  v += p[i + 3 * S];
  out[i] = v;
}

// Unified GEMM, global_load_lds(16B) staging, XOR-swizzled unpadded LDS.
// C[r,n] = act(biasv[n] + sum_k A[base(r)+kOff+k] * Bt[n*Ktot + bOffB + kOff + k])
// base(r) = (r + (r/RPB)*EXTRA) * BSCALE.  SPLITK: blockIdx.z selects k-chunk,
// partials written f32 at outp + z*M*512. TRANS: out[bb, n, t] bf16 via LDS repack.
template<int BM, int BN, bool RELU, bool OBF16, bool TRANS, bool SPLITK>
__global__ __launch_bounds__(256)
void gemm_bt(const unsigned short* __restrict__ A,
             const unsigned short* __restrict__ Bt,
             const float* __restrict__ biasv,
             void* __restrict__ outp,
             int M, int Kchunk, int RPB, int EXTRA, int BSCALE,
             long long bStrideB, long long outBatchStride, int outLd)
{
  constexpr int WM = BM / 2, WN = BN / 2;
  constexpr int NI = WM / 16, NJ = WN / 16;
  constexpr int AI = BM / 64;                 // glds instrs per wave (A)
  constexpr int BI = BN / 64;
  constexpr int SA = BM * 32, SB = BN * 32;   // shorts, unpadded rows of 32
  constexpr int SMEMN = TRANS ? ((128 * 136 > SA + SB) ? 128 * 136 : SA + SB) : (SA + SB);
  __shared__ unsigned short smem[SMEMN];

  const int tid  = threadIdx.x;
  const int lane = tid & 63;
  const int wave = tid >> 6;
  const int wm = wave >> 1, wn = wave & 1;
  const int lr = lane & 15, quad = lane >> 4;

  const int r0 = blockIdx.x * BM;
  const int n0 = blockIdx.y * BN;
  const int bb = r0 / RPB;
  const int Ktot = SPLITK ? Kchunk * gridDim.z : Kchunk;
  const int kOff = SPLITK ? blockIdx.z * Kchunk : 0;
  const long long bOffB = (long long)bb * bStrideB;

  // staging descriptors: instr = c*4+wave covers 16 tile rows; lane -> (row, seg)
  // LDS slot (row, s) holds global chunk s^(row&3)  [XOR swizzle]
  const int srow = lane >> 2;
  const int sg = (lane & 3) ^ (srow & 3);
  const unsigned short* gA[AI]; const unsigned short* ldsA[AI];
#pragma unroll
  for (int c = 0; c < AI; ++c) {
    int instr = c * 4 + wave;
    int row = instr * 16 + srow;
    int r = r0 + row; if (r > M - 1) r = M - 1;          // clamp partial tiles
    gA[c] = A + ((long long)r + (long long)(r / RPB) * EXTRA) * BSCALE + kOff + sg * 8;
    ldsA[c] = smem + instr * 512;
  }
  const unsigned short* gB[BI]; const unsigned short* ldsB[BI];
#pragma unroll
  for (int c = 0; c < BI; ++c) {
    int instr = c * 4 + wave;
    int row = instr * 16 + srow;
    gB[c] = Bt + (long long)(n0 + row) * Ktot + bOffB + kOff + sg * 8;
    ldsB[c] = smem + SA + instr * 512;
  }

  // reader fragment offsets (shorts), swizzle-matched, loop-invariant
  int aoff[NI], boff[NJ];
#pragma unroll
  for (int i = 0; i < NI; ++i) {
    int rr = wm * WM + i * 16 + lr;
    aoff[i] = rr * 32 + ((quad ^ (rr & 3)) * 8);
  }
#pragma unroll
  for (int j = 0; j < NJ; ++j) {
    int rr = wn * WN + j * 16 + lr;
    boff[j] = SA + rr * 32 + ((quad ^ (rr & 3)) * 8);
  }

  float4v acc[NI][NJ];
  const float4v z4 = {0.f, 0.f, 0.f, 0.f};
#pragma unroll
  for (int i = 0; i < NI; ++i)
#pragma unroll
    for (int j = 0; j < NJ; ++j) acc[i][j] = z4;

  for (int k0 = 0; k0 < Kchunk; k0 += 32) {
#pragma unroll
    for (int c = 0; c < AI; ++c)
      __builtin_amdgcn_global_load_lds((gu32*)(gA[c] + k0), (lu32*)(ldsA[c]), 16, 0, 0);
#pragma unroll
    for (int c = 0; c < BI; ++c)
      __builtin_amdgcn_global_load_lds((gu32*)(gB[c] + k0), (lu32*)(ldsB[c]), 16, 0, 0);
    __syncthreads();
    short8 af[NI], bfr[NJ];
#pragma unroll
    for (int i = 0; i < NI; ++i) af[i] = *(const short8*)(smem + aoff[i]);
#pragma unroll
    for (int j = 0; j < NJ; ++j) bfr[j] = *(const short8*)(smem + boff[j]);
#pragma unroll
    for (int i = 0; i < NI; ++i)
#pragma unroll
      for (int j = 0; j < NJ; ++j)
        acc[i][j] = __builtin_amdgcn_mfma_f32_16x16x32_bf16(af[i], bfr[j], acc[i][j], 0, 0, 0);
    __syncthreads();
  }

  if (TRANS) {
    // repack D (t,f) -> LDS (f-major, stride 136: 16B-aligned rows, 2-way conflicts)
    unsigned short* Ts = smem;
#pragma unroll
    for (int j = 0; j < NJ; ++j) {
      int fr = wn * WN + j * 16 + lr;
      float bv = biasv[n0 + fr];
#pragma unroll
      for (int i = 0; i < NI; ++i) {
        int tr = wm * WM + i * 16 + quad * 4;
        unsigned long long pk = 0;
#pragma unroll
        for (int g = 0; g < 4; ++g)
          pk |= (unsigned long long)f2bf(acc[i][j][g] + bv) << (16 * g);
        *(unsigned long long*)(Ts + fr * 136 + tr) = pk;
      }
    }
    __syncthreads();
    int fr = tid >> 1, sgg = tid & 1;
    int t0l = r0 - bb * RPB;
    unsigned short* dst = (unsigned short*)outp + (long long)bb * outBatchStride
                        + (long long)(n0 + fr) * outLd + t0l + sgg * 64;
    const unsigned short* srcp = Ts + fr * 136 + sgg * 64;
#pragma unroll
    for (int u = 0; u < 8; ++u)
      *(uint4*)(dst + u * 8) = *(const uint4*)(srcp + u * 8);
  } else {
    float* outF = (float*)outp;
    if (SPLITK) outF += (long long)blockIdx.z * M * 512;
#pragma unroll
    for (int j = 0; j < NJ; ++j) {
      int n_g = n0 + wn * WN + j * 16 + lr;
      float bv = biasv ? biasv[n_g] : 0.f;
#pragma unroll
      for (int i = 0; i < NI; ++i) {
        int r_base = r0 + wm * WM + i * 16 + quad * 4;
#pragma unroll
        for (int g = 0; g < 4; ++g) {
          int r_g = r_base + g;
          if (r_g >= M) continue;
          float v = acc[i][j][g] + bv;
          if (RELU) v = fmaxf(v, 0.f);
          long long oidx = (long long)r_g * 512 + n_g;
          if (OBF16) ((unsigned short*)outp)[oidx] = f2bf(v);
          else       outF[oidx] = v;
        }
      }
    }
  }
}

extern "C" void kernel_launch(void* const* d_in, const int* in_sizes, int n_in,
                              void* d_out, int out_size, void* d_ws, size_t ws_size,
                              hipStream_t stream) {
  const float* x   = (const float*)d_in[0];
  const float* z   = (const float*)d_in[1];
  const float* ww1 = (const float*)d_in[2];
  const float* wb1 = (const float*)d_in[3];
  const float* ww2 = (const float*)d_in[4];
  const float* wb2 = (const float*)d_in[5];
  const float* bw1 = (const float*)d_in[6];
  const float* bb1 = (const float*)d_in[7];
  const float* bw2 = (const float*)d_in[8];
  const float* bb2 = (const float*)d_in[9];

  char* ws = (char*)d_ws;
  unsigned short* xb  = (unsigned short*)ws; ws += 16777216ll * 2;  // (8,512,4096) shifted bf16
  unsigned short* zb  = (unsigned short*)ws; ws += 4196352ll  * 2;  // (8,4098,128) bf16
  unsigned short* h1w = (unsigned short*)ws; ws += 16781312ll * 2;  // (8,4097,512) bf16; reused as splitK partials
  unsigned short* wT  = (unsigned short*)ws; ws += 16777216ll * 2;  // (8,512,4096) WtT bf16
  unsigned short* h1b = (unsigned short*)ws; ws += 2101248ll  * 2;  // (8,513,512) bf16
  float*          bM  = (float*)ws;          ws += 2097152ll  * 4;  // (8,512,512) f32
  unsigned short* w1T = (unsigned short*)ws; ws += 131072ll * 2;    // (512,256)
  unsigned short* w2T = (unsigned short*)ws; ws += 524288ll * 2;    // (512,1024)
  unsigned short* b1T = (unsigned short*)ws; ws += 131072ll * 2;
  unsigned short* b2T = (unsigned short*)ws; ws += 524288ll * 2;
  float* parts = (float*)h1w;                                       // 4 x (4096x512) f32

  transpose_w<<<(256 * 512) / 256, 256, 0, stream>>>(ww1, w1T, 256);
  transpose_w<<<(1024 * 512) / 256, 256, 0, stream>>>(ww2, w2T, 1024);
  transpose_w<<<(256 * 512) / 256, 256, 0, stream>>>(bw1, b1T, 256);
  transpose_w<<<(1024 * 512) / 256, 256, 0, stream>>>(bw2, b2T, 1024);
  cvt_plain<<<(4196352 + 255) / 256, 256, 0, stream>>>(z, zb, 4196352);
  cvt_shift_x<<<(16777216 + 255) / 256, 256, 0, stream>>>(x, xb, 16777216);

  // conv1-w: h1w = relu(z * w1 + wb1), M=8*4097, K=256, base=(r + b)*128
  gemm_bt<128, 128, true, true, false, false><<<dim3(257, 4), 256, 0, stream>>>(
      zb, w1T, wb1, h1w, 32776, 256, 4097, 1, 128, 0, 0, 512);
  // conv1-b (truncated t<513): M=8*513, base=(r + 3585*b)*128
  gemm_bt<64, 128, true, true, false, false><<<dim3(65, 4), 256, 0, stream>>>(
      zb, b1T, bb1, h1b, 4104, 256, 513, 3585, 128, 0, 0, 512);
  // conv2-w -> WtT (transposed store): M=8*4096, K=1024, base=(r + b)*512
  gemm_bt<128, 128, false, true, true, false><<<dim3(256, 4), 256, 0, stream>>>(
      h1w, w2T, wb2, wT, 32768, 1024, 4096, 1, 512, 0, 512ll * 4096, 4096);
  // conv2-b -> bM f32 (includes bb2): M=8*512, base=(r + b)*512
  gemm_bt<64, 128, false, false, false, false><<<dim3(64, 4), 256, 0, stream>>>(
      h1b, b2T, bb2, bM, 4096, 1024, 512, 1, 512, 0, 0, 512);
  // main split-K x4: parts[z] = xshift @ W (per-batch B), M=8*512, Ktot=4096
  gemm_bt<64, 128, false, false, false, true><<<dim3(64, 4, 4), 256, 0, stream>>>(
      xb, wT, nullptr, parts, 4096, 1024, 512, 0, 4096, 512ll * 4096, 0, 512);
  // out = bM + sum parts
  reduce_out<<<2048, 256, 0, stream>>>((const float4v*)parts, (const float4v*)bM, (float4v*)d_out);
}

// Round 3
// 323.392 us; speedup vs baseline: 1.2012x; 1.1571x over previous
//
#include <hip/hip_runtime.h>

typedef short short8 __attribute__((ext_vector_type(8)));
typedef float float4v __attribute__((ext_vector_type(4)));
typedef __attribute__((address_space(1))) const unsigned int gu32;
typedef __attribute__((address_space(3))) unsigned int lu32;

__device__ __forceinline__ unsigned short f2bf(float f) {
  unsigned int u = __builtin_bit_cast(unsigned int, f);
  u += 0x7FFFu + ((u >> 16) & 1u);   // round-to-nearest-even
  return (unsigned short)(u >> 16);
}

__global__ void cvt_plain(const float* __restrict__ s, unsigned short* __restrict__ d, int n) {
  int i = blockIdx.x * 256 + threadIdx.x;
  if (i >= n) return;
  d[i] = f2bf(s[i]);
}

// src (K,512) f32 row-major -> dst (512,K) bf16 row-major (B-operand layout)
__global__ void transpose_w(const float* __restrict__ src, unsigned short* __restrict__ dst, int K) {
  int i = blockIdx.x * 256 + threadIdx.x;
  if (i >= K * 512) return;
  int n = i & 511, k = i >> 9;
  dst[n * K + k] = f2bf(src[i]);
}

// One block per row r (4096 rows of 4096). Produces:
//   xs[r,t] = bf16(x[r,t+1]), 0 at t=4095   (shifted A for G_lo)
//   xz[r,t] = bf16(x[r,t]),   0 at t=0      (zeroed A for G_hi)
//   rs[r]   = sum_t f32(xs[r,t])            (rank-1 wb2 coefficient)
__global__ __launch_bounds__(256) void cvt_x(const float* __restrict__ x,
                                             unsigned short* __restrict__ xs,
                                             unsigned short* __restrict__ xz,
                                             float* __restrict__ rs) {
  __shared__ float red[4];
  long long r = blockIdx.x;
  const float* xr = x + r * 4096;
  int t0 = threadIdx.x * 16;
  float v[17];
  const float4* xr4 = (const float4*)(xr + t0);
#pragma unroll
  for (int q = 0; q < 4; ++q) {
    float4 f = xr4[q];
    v[q * 4] = f.x; v[q * 4 + 1] = f.y; v[q * 4 + 2] = f.z; v[q * 4 + 3] = f.w;
  }
  v[16] = (t0 + 16 < 4096) ? xr[t0 + 16] : 0.f;
  unsigned int spk[8], zpk[8];
  float sum = 0.f;
#pragma unroll
  for (int q = 0; q < 8; ++q) {
    unsigned short s0 = f2bf(v[2 * q + 1]);
    unsigned short s1 = f2bf(v[2 * q + 2]);
    sum += __builtin_bit_cast(float, (unsigned int)s0 << 16);
    sum += __builtin_bit_cast(float, (unsigned int)s1 << 16);
    spk[q] = (unsigned int)s0 | ((unsigned int)s1 << 16);
    unsigned short z0 = (t0 == 0 && q == 0) ? (unsigned short)0 : f2bf(v[2 * q]);
    unsigned short z1 = f2bf(v[2 * q + 1]);
    zpk[q] = (unsigned int)z0 | ((unsigned int)z1 << 16);
  }
  *(uint4*)(xs + r * 4096 + t0)     = *(uint4*)(spk);
  *(uint4*)(xs + r * 4096 + t0 + 8) = *(uint4*)(spk + 4);
  *(uint4*)(xz + r * 4096 + t0)     = *(uint4*)(zpk);
  *(uint4*)(xz + r * 4096 + t0 + 8) = *(uint4*)(zpk + 4);
#pragma unroll
  for (int off = 32; off > 0; off >>= 1) sum += __shfl_down(sum, off);
  if ((threadIdx.x & 63) == 0) red[threadIdx.x >> 6] = sum;
  __syncthreads();
  if (threadIdx.x == 0) rs[r] = red[0] + red[1] + red[2] + red[3];
}

// Unified GEMM, global_load_lds(16B) staging, XOR-swizzled unpadded LDS.
// C[r,n] = act(biasv[n] + sum_k Ae[base(r)+k] * Bt[((n)&bRowMask)*K + bOffB + k])
// base(r) = (r + (r/RPB)*EXTRA) * BSCALE;  Ae = (nHalf && n0>=nHalf) ? A2 : A.
// Plain store: out[r*outLd+n] (f32 or bf16); ADDM: += addm[r*outLd+n] + rsv[r]*b2v[n].
// TRANS store: out[bb*outBatchStride + (n0+f)*outLd + t_local]  (bf16, LDS repack).
template<int BM, int BN, bool RELU, bool OBF16, bool TRANS, bool ADDM>
__global__ __launch_bounds__(256)
void gemm_bt(const unsigned short* __restrict__ A,
             const unsigned short* __restrict__ A2,
             const unsigned short* __restrict__ Bt,
             const float* __restrict__ biasv,
             const float* __restrict__ addm,
             const float* __restrict__ rsv,
             const float* __restrict__ b2v,
             void* __restrict__ outp,
             int M, int K, int RPB, int EXTRA, int BSCALE,
             int nHalf, int bRowMask,
             long long bStrideB, long long outBatchStride, int outLd)
{
  constexpr int WM = BM / 2, WN = BN / 2;
  constexpr int NI = WM / 16, NJ = WN / 16;
  constexpr int AI = BM / 64;                 // glds instrs per wave (A)
  constexpr int BI = BN / 64;
  constexpr int SA = BM * 32, SB = BN * 32;   // shorts, unpadded rows of 32
  constexpr int SMEMN = TRANS ? ((128 * 136 > SA + SB) ? 128 * 136 : SA + SB) : (SA + SB);
  __shared__ unsigned short smem[SMEMN];

  const int tid  = threadIdx.x;
  const int lane = tid & 63;
  const int wave = tid >> 6;
  const int wm = wave >> 1, wn = wave & 1;
  const int lr = lane & 15, quad = lane >> 4;

  const int r0 = blockIdx.x * BM;
  const int n0 = blockIdx.y * BN;
  const int bb = r0 / RPB;
  const long long bOffB = (long long)bb * bStrideB;
  const unsigned short* Ae = (nHalf && n0 >= nHalf) ? A2 : A;

  // staging: instr = c*4+wave covers 16 tile rows; lane -> (row, seg)
  // LDS slot (row, s) holds global chunk s^(row&3)  [XOR swizzle]
  const int srow = lane >> 2;
  const int sg = (lane & 3) ^ (srow & 3);
  const unsigned short* gA[AI]; const unsigned short* ldsA[AI];
#pragma unroll
  for (int c = 0; c < AI; ++c) {
    int instr = c * 4 + wave;
    int row = instr * 16 + srow;
    int r = r0 + row; if (r > M - 1) r = M - 1;          // clamp partial tiles
    gA[c] = Ae + ((long long)r + (long long)(r / RPB) * EXTRA) * BSCALE + sg * 8;
    ldsA[c] = smem + instr * 512;
  }
  const unsigned short* gB[BI]; const unsigned short* ldsB[BI];
#pragma unroll
  for (int c = 0; c < BI; ++c) {
    int instr = c * 4 + wave;
    int row = instr * 16 + srow;
    gB[c] = Bt + (long long)((n0 + row) & bRowMask) * K + bOffB + sg * 8;
    ldsB[c] = smem + SA + instr * 512;
  }

  // reader fragment offsets (shorts), swizzle-matched, loop-invariant
  int aoff[NI], boff[NJ];
#pragma unroll
  for (int i = 0; i < NI; ++i) {
    int rr = wm * WM + i * 16 + lr;
    aoff[i] = rr * 32 + ((quad ^ (rr & 3)) * 8);
  }
#pragma unroll
  for (int j = 0; j < NJ; ++j) {
    int rr = wn * WN + j * 16 + lr;
    boff[j] = SA + rr * 32 + ((quad ^ (rr & 3)) * 8);
  }

  float4v acc[NI][NJ];
  const float4v z4 = {0.f, 0.f, 0.f, 0.f};
#pragma unroll
  for (int i = 0; i < NI; ++i)
#pragma unroll
    for (int j = 0; j < NJ; ++j) acc[i][j] = z4;

  for (int k0 = 0; k0 < K; k0 += 32) {
#pragma unroll
    for (int c = 0; c < AI; ++c)
      __builtin_amdgcn_global_load_lds((gu32*)(gA[c] + k0), (lu32*)(ldsA[c]), 16, 0, 0);
#pragma unroll
    for (int c = 0; c < BI; ++c)
      __builtin_amdgcn_global_load_lds((gu32*)(gB[c] + k0), (lu32*)(ldsB[c]), 16, 0, 0);
    __syncthreads();
    short8 af[NI], bfr[NJ];
#pragma unroll
    for (int i = 0; i < NI; ++i) af[i] = *(const short8*)(smem + aoff[i]);
#pragma unroll
    for (int j = 0; j < NJ; ++j) bfr[j] = *(const short8*)(smem + boff[j]);
#pragma unroll
    for (int i = 0; i < NI; ++i)
#pragma unroll
      for (int j = 0; j < NJ; ++j)
        acc[i][j] = __builtin_amdgcn_mfma_f32_16x16x32_bf16(af[i], bfr[j], acc[i][j], 0, 0, 0);
    __syncthreads();
  }

  if (TRANS) {
    // repack D (t,f) -> LDS (f-major, stride 136: 16B-aligned rows, 2-way conflicts)
    unsigned short* Ts = smem;
#pragma unroll
    for (int j = 0; j < NJ; ++j) {
      int fr = wn * WN + j * 16 + lr;
      float bv = biasv[n0 + fr];
#pragma unroll
      for (int i = 0; i < NI; ++i) {
        int tr = wm * WM + i * 16 + quad * 4;
        unsigned long long pk = 0;
#pragma unroll
        for (int g = 0; g < 4; ++g) {
          float vv = acc[i][j][g] + bv;
          if (RELU) vv = fmaxf(vv, 0.f);
          pk |= (unsigned long long)f2bf(vv) << (16 * g);
        }
        *(unsigned long long*)(Ts + fr * 136 + tr) = pk;
      }
    }
    __syncthreads();
    int fr = tid >> 1, sgg = tid & 1;
    int t0l = r0 - bb * RPB;
    unsigned short* dst = (unsigned short*)outp + (long long)bb * outBatchStride
                        + (long long)(n0 + fr) * outLd + t0l + sgg * 64;
    const unsigned short* srcp = Ts + fr * 136 + sgg * 64;
#pragma unroll
    for (int u = 0; u < 8; ++u)
      *(uint4*)(dst + u * 8) = *(const uint4*)(srcp + u * 8);
  } else {
#pragma unroll
    for (int j = 0; j < NJ; ++j) {
      int n_g = n0 + wn * WN + j * 16 + lr;
      float bv = biasv ? biasv[n_g] : 0.f;
      float b2 = ADDM ? b2v[n_g] : 0.f;
#pragma unroll
      for (int i = 0; i < NI; ++i) {
        int r_base = r0 + wm * WM + i * 16 + quad * 4;
#pragma unroll
        for (int g = 0; g < 4; ++g) {
          int r_g = r_base + g;
          if (r_g >= M) continue;
          float v = acc[i][j][g] + bv;
          if (RELU) v = fmaxf(v, 0.f);
          long long oidx = (long long)r_g * outLd + n_g;
          if (ADDM) v += addm[oidx] + rsv[r_g] * b2;
          if (OBF16) ((unsigned short*)outp)[oidx] = f2bf(v);
          else       ((float*)outp)[oidx] = v;
        }
      }
    }
  }
}

extern "C" void kernel_launch(void* const* d_in, const int* in_sizes, int n_in,
                              void* d_out, int out_size, void* d_ws, size_t ws_size,
                              hipStream_t stream) {
  const float* x   = (const float*)d_in[0];
  const float* z   = (const float*)d_in[1];
  const float* ww1 = (const float*)d_in[2];
  const float* wb1 = (const float*)d_in[3];
  const float* ww2 = (const float*)d_in[4];
  const float* wb2 = (const float*)d_in[5];
  const float* bw1 = (const float*)d_in[6];
  const float* bb1 = (const float*)d_in[7];
  const float* bw2 = (const float*)d_in[8];
  const float* bb2 = (const float*)d_in[9];

  char* ws = (char*)d_ws;
  unsigned short* xs  = (unsigned short*)ws; ws += 16777216ll * 2;  // (8,512,4096) shifted bf16
  unsigned short* xz  = (unsigned short*)ws; ws += 16777216ll * 2;  // (8,512,4096) t0-zeroed bf16
  unsigned short* zb  = (unsigned short*)ws; ws += 4196352ll  * 2;  // (8,4098,128) bf16; later reused as G
  unsigned short* h1T = (unsigned short*)ws; ws += 16777216ll * 2;  // (8,512,4096) h1 transposed bf16
  unsigned short* h1b = (unsigned short*)ws; ws += 2101248ll  * 2;  // (8,513,512) bias-path h1 bf16
  unsigned short* w1T = (unsigned short*)ws; ws += 131072ll * 2;    // (512,256)
  unsigned short* w2T = (unsigned short*)ws; ws += 524288ll * 2;    // (512,1024)
  unsigned short* b1T = (unsigned short*)ws; ws += 131072ll * 2;
  unsigned short* b2T = (unsigned short*)ws; ws += 524288ll * 2;
  float* rs = (float*)ws;                    ws += 4096ll * 4;      // rowsum(xs)
  unsigned short* G = zb;                    // (8,512,1024) bf16, overlays zb (dead after conv1-b)
  float* bM = (float*)d_out;                 // bias matrix written directly into d_out

  transpose_w<<<(256 * 512) / 256, 256, 0, stream>>>(ww1, w1T, 256);
  transpose_w<<<(1024 * 512) / 256, 256, 0, stream>>>(ww2, w2T, 1024);
  transpose_w<<<(256 * 512) / 256, 256, 0, stream>>>(bw1, b1T, 256);
  transpose_w<<<(1024 * 512) / 256, 256, 0, stream>>>(bw2, b2T, 1024);
  cvt_plain<<<(4196352 + 255) / 256, 256, 0, stream>>>(z, zb, 4196352);
  cvt_x<<<4096, 256, 0, stream>>>(x, xs, xz, rs);

  // conv1-w -> h1T (TRANS, relu): M=8*4096, K=256, A row = (r + 2b)*128
  gemm_bt<128, 128, true, true, true, false><<<dim3(256, 4), 256, 0, stream>>>(
      zb, nullptr, w1T, wb1, nullptr, nullptr, nullptr, h1T,
      32768, 256, 4096, 2, 128, 0, 0xFFFF, 0, 512ll * 4096, 4096);
  // conv1-b (t<513): M=8*513, A row = (r + 3585b)*128 -> h1b bf16
  gemm_bt<64, 128, true, true, false, false><<<dim3(65, 4), 256, 0, stream>>>(
      zb, nullptr, b1T, bb1, nullptr, nullptr, nullptr, h1b,
      4104, 256, 513, 3585, 128, 0, 0xFFFF, 0, 0, 512);
  // conv2-b -> bM (= d_out) f32, includes bb2: M=8*512, A row = (r + b)*512
  gemm_bt<64, 128, false, false, false, false><<<dim3(64, 4), 256, 0, stream>>>(
      h1b, nullptr, b2T, bb2, nullptr, nullptr, nullptr, bM,
      4096, 1024, 512, 1, 512, 0, 0xFFFF, 0, 0, 512);
  // G = [xs ; xz] @ h1T^T : M=4096, N=1024, K=4096, B per-batch, bRowMask=511
  gemm_bt<64, 128, false, true, false, false><<<dim3(64, 8), 256, 0, stream>>>(
      xs, xz, h1T, nullptr, nullptr, nullptr, nullptr, G,
      4096, 4096, 512, 0, 4096, 512, 511, 512ll * 4096, 0, 1024);
  // out = G @ w2 + bM(already in d_out) + rs x wb2 : M=4096, N=512, K=1024
  gemm_bt<64, 64, false, false, false, true><<<dim3(64, 8), 256, 0, stream>>>(
      G, nullptr, w2T, nullptr, bM, rs, wb2, d_out,
      4096, 1024, 4096, 0, 1024, 0, 0xFFFF, 0, 0, 512);
}

// Round 4
// 306.398 us; speedup vs baseline: 1.2678x; 1.0555x over previous
//
#include <hip/hip_runtime.h>

typedef short short8 __attribute__((ext_vector_type(8)));
typedef float float4v __attribute__((ext_vector_type(4)));
typedef __attribute__((address_space(1))) const unsigned int gu32;
typedef __attribute__((address_space(3))) unsigned int lu32;

__device__ __forceinline__ unsigned short f2bf(float f) {
  unsigned int u = __builtin_bit_cast(unsigned int, f);
  u += 0x7FFFu + ((u >> 16) & 1u);   // round-to-nearest-even
  return (unsigned short)(u >> 16);
}
__device__ __forceinline__ float bf2f(unsigned short s) {
  return __builtin_bit_cast(float, (unsigned int)s << 16);
}

// One kernel for all weight transposes + z conversion.
// Regions (element counts): ww1 131072, ww2 524288, bw1 131072, bw2 524288, z 4196352.
__global__ __launch_bounds__(256) void prep_all(
    const float* __restrict__ ww1, const float* __restrict__ ww2,
    const float* __restrict__ bw1, const float* __restrict__ bw2,
    const float* __restrict__ z,
    unsigned short* __restrict__ w1T, unsigned short* __restrict__ w2T,
    unsigned short* __restrict__ b1T, unsigned short* __restrict__ b2T,
    unsigned short* __restrict__ zb)
{
  int i = blockIdx.x * 256 + threadIdx.x;
  if (i < 131072) {
    int n = i & 511, k = i >> 9;
    w1T[n * 256 + k] = f2bf(ww1[i]);
  } else if (i < 655360) {
    int j = i - 131072; int n = j & 511, k = j >> 9;
    w2T[n * 1024 + k] = f2bf(ww2[j]);
  } else if (i < 786432) {
    int j = i - 655360; int n = j & 511, k = j >> 9;
    b1T[n * 256 + k] = f2bf(bw1[j]);
  } else if (i < 1310720) {
    int j = i - 786432; int n = j & 511, k = j >> 9;
    b2T[n * 1024 + k] = f2bf(bw2[j]);
  } else {
    int j = i - 1310720;
    zb[j] = f2bf(z[j]);
  }
}

// One block per row r (4096 rows of 4096). Produces:
//   xs[r,t] = bf16(x[r,t+1]), 0 at t=4095   (shifted A for G_lo)
//   xz[r,t] = bf16(x[r,t]),   0 at t=0      (zeroed A for G_hi)
//   rs[r]   = sum_t f32(xs[r,t])            (rank-1 wb2 coefficient)
__global__ __launch_bounds__(256) void cvt_x(const float* __restrict__ x,
                                             unsigned short* __restrict__ xs,
                                             unsigned short* __restrict__ xz,
                                             float* __restrict__ rs) {
  __shared__ float red[4];
  long long r = blockIdx.x;
  const float* xr = x + r * 4096;
  int t0 = threadIdx.x * 16;
  float v[17];
  const float4* xr4 = (const float4*)(xr + t0);
#pragma unroll
  for (int q = 0; q < 4; ++q) {
    float4 f = xr4[q];
    v[q * 4] = f.x; v[q * 4 + 1] = f.y; v[q * 4 + 2] = f.z; v[q * 4 + 3] = f.w;
  }
  v[16] = (t0 + 16 < 4096) ? xr[t0 + 16] : 0.f;
  unsigned int spk[8], zpk[8];
  float sum = 0.f;
#pragma unroll
  for (int q = 0; q < 8; ++q) {
    unsigned short s0 = f2bf(v[2 * q + 1]);
    unsigned short s1 = f2bf(v[2 * q + 2]);
    sum += bf2f(s0);
    sum += bf2f(s1);
    spk[q] = (unsigned int)s0 | ((unsigned int)s1 << 16);
    unsigned short z0 = (t0 == 0 && q == 0) ? (unsigned short)0 : f2bf(v[2 * q]);
    unsigned short z1 = f2bf(v[2 * q + 1]);
    zpk[q] = (unsigned int)z0 | ((unsigned int)z1 << 16);
  }
  *(uint4*)(xs + r * 4096 + t0)     = *(uint4*)(spk);
  *(uint4*)(xs + r * 4096 + t0 + 8) = *(uint4*)(spk + 4);
  *(uint4*)(xz + r * 4096 + t0)     = *(uint4*)(zpk);
  *(uint4*)(xz + r * 4096 + t0 + 8) = *(uint4*)(zpk + 4);
#pragma unroll
  for (int off = 32; off > 0; off >>= 1) sum += __shfl_down(sum, off);
  if ((threadIdx.x & 63) == 0) red[threadIdx.x >> 6] = sum;
  __syncthreads();
  if (threadIdx.x == 0) rs[r] = red[0] + red[1] + red[2] + red[3];
}

// Unified GEMM, global_load_lds(16B) staging, XOR-swizzled unpadded LDS.
// C[r,n] = act(biasv[n] + sum_k Ae[base(r)+kOff+k] * Bt[((n)&bRowMask)*Ktot + bOffB + kOff + k])
// base(r) = (r + (r/RPB)*EXTRA) * BSCALE;  Ae = (nHalf && n0>=nHalf) ? A2 : A.
// SPLITK: blockIdx.z picks k-chunk; z=0 -> outp, z=1 -> outp2 (bf16).
// TRANS store: out[bb*outBatchStride + (n0+f)*outLd + t_local]  (bf16, LDS repack).
template<int BM, int BN, bool RELU, bool OBF16, bool TRANS, bool SPLITK>
__global__ __launch_bounds__(256)
void gemm_bt(const unsigned short* __restrict__ A,
             const unsigned short* __restrict__ A2,
             const unsigned short* __restrict__ Bt,
             const float* __restrict__ biasv,
             void* __restrict__ outp,
             void* __restrict__ outp2,
             int M, int Kchunk, int RPB, int EXTRA, int BSCALE,
             int nHalf, int bRowMask,
             long long bStrideB, long long outBatchStride, int outLd)
{
  constexpr int WM = BM / 2, WN = BN / 2;
  constexpr int NI = WM / 16, NJ = WN / 16;
  constexpr int AI = BM / 64;                 // glds instrs per wave (A)
  constexpr int BI = BN / 64;
  constexpr int SA = BM * 32, SB = BN * 32;   // shorts, unpadded rows of 32
  constexpr int SMEMN = TRANS ? ((128 * 136 > SA + SB) ? 128 * 136 : SA + SB) : (SA + SB);
  __shared__ unsigned short smem[SMEMN];

  const int tid  = threadIdx.x;
  const int lane = tid & 63;
  const int wave = tid >> 6;
  const int wm = wave >> 1, wn = wave & 1;
  const int lr = lane & 15, quad = lane >> 4;

  const int r0 = blockIdx.x * BM;
  const int n0 = blockIdx.y * BN;
  const int bb = r0 / RPB;
  const int Ktot = SPLITK ? Kchunk * gridDim.z : Kchunk;
  const int kOff = SPLITK ? blockIdx.z * Kchunk : 0;
  const long long bOffB = (long long)bb * bStrideB;
  const unsigned short* Ae = (nHalf && n0 >= nHalf) ? A2 : A;

  // staging: instr = c*4+wave covers 16 tile rows; lane -> (row, seg)
  // LDS slot (row, s) holds global chunk s^(row&3)  [XOR swizzle]
  const int srow = lane >> 2;
  const int sg = (lane & 3) ^ (srow & 3);
  const unsigned short* gA[AI]; const unsigned short* ldsA[AI];
#pragma unroll
  for (int c = 0; c < AI; ++c) {
    int instr = c * 4 + wave;
    int row = instr * 16 + srow;
    int r = r0 + row; if (r > M - 1) r = M - 1;          // clamp partial tiles
    gA[c] = Ae + ((long long)r + (long long)(r / RPB) * EXTRA) * BSCALE + kOff + sg * 8;
    ldsA[c] = smem + instr * 512;
  }
  const unsigned short* gB[BI]; const unsigned short* ldsB[BI];
#pragma unroll
  for (int c = 0; c < BI; ++c) {
    int instr = c * 4 + wave;
    int row = instr * 16 + srow;
    gB[c] = Bt + (long long)((n0 + row) & bRowMask) * Ktot + bOffB + kOff + sg * 8;
    ldsB[c] = smem + SA + instr * 512;
  }

  // reader fragment offsets (shorts), swizzle-matched, loop-invariant
  int aoff[NI], boff[NJ];
#pragma unroll
  for (int i = 0; i < NI; ++i) {
    int rr = wm * WM + i * 16 + lr;
    aoff[i] = rr * 32 + ((quad ^ (rr & 3)) * 8);
  }
#pragma unroll
  for (int j = 0; j < NJ; ++j) {
    int rr = wn * WN + j * 16 + lr;
    boff[j] = SA + rr * 32 + ((quad ^ (rr & 3)) * 8);
  }

  float4v acc[NI][NJ];
  const float4v z4 = {0.f, 0.f, 0.f, 0.f};
#pragma unroll
  for (int i = 0; i < NI; ++i)
#pragma unroll
    for (int j = 0; j < NJ; ++j) acc[i][j] = z4;

  for (int k0 = 0; k0 < Kchunk; k0 += 32) {
#pragma unroll
    for (int c = 0; c < AI; ++c)
      __builtin_amdgcn_global_load_lds((gu32*)(gA[c] + k0), (lu32*)(ldsA[c]), 16, 0, 0);
#pragma unroll
    for (int c = 0; c < BI; ++c)
      __builtin_amdgcn_global_load_lds((gu32*)(gB[c] + k0), (lu32*)(ldsB[c]), 16, 0, 0);
    __syncthreads();
    short8 af[NI], bfr[NJ];
#pragma unroll
    for (int i = 0; i < NI; ++i) af[i] = *(const short8*)(smem + aoff[i]);
#pragma unroll
    for (int j = 0; j < NJ; ++j) bfr[j] = *(const short8*)(smem + boff[j]);
#pragma unroll
    for (int i = 0; i < NI; ++i)
#pragma unroll
      for (int j = 0; j < NJ; ++j)
        acc[i][j] = __builtin_amdgcn_mfma_f32_16x16x32_bf16(af[i], bfr[j], acc[i][j], 0, 0, 0);
    __syncthreads();
  }

  if (TRANS) {
    // repack D (t,f) -> LDS (f-major, stride 136: 16B-aligned rows, 2-way conflicts)
    unsigned short* Ts = smem;
#pragma unroll
    for (int j = 0; j < NJ; ++j) {
      int fr = wn * WN + j * 16 + lr;
      float bv = biasv[n0 + fr];
#pragma unroll
      for (int i = 0; i < NI; ++i) {
        int tr = wm * WM + i * 16 + quad * 4;
        unsigned long long pk = 0;
#pragma unroll
        for (int g = 0; g < 4; ++g) {
          float vv = acc[i][j][g] + bv;
          if (RELU) vv = fmaxf(vv, 0.f);
          pk |= (unsigned long long)f2bf(vv) << (16 * g);
        }
        *(unsigned long long*)(Ts + fr * 136 + tr) = pk;
      }
    }
    __syncthreads();
    int fr = tid >> 1, sgg = tid & 1;
    int t0l = r0 - bb * RPB;
    unsigned short* dst = (unsigned short*)outp + (long long)bb * outBatchStride
                        + (long long)(n0 + fr) * outLd + t0l + sgg * 64;
    const unsigned short* srcp = Ts + fr * 136 + sgg * 64;
#pragma unroll
    for (int u = 0; u < 8; ++u)
      *(uint4*)(dst + u * 8) = *(const uint4*)(srcp + u * 8);
  } else {
    void* op = (SPLITK && blockIdx.z) ? outp2 : outp;
#pragma unroll
    for (int j = 0; j < NJ; ++j) {
      int n_g = n0 + wn * WN + j * 16 + lr;
      float bv = biasv ? biasv[n_g] : 0.f;
#pragma unroll
      for (int i = 0; i < NI; ++i) {
        int r_base = r0 + wm * WM + i * 16 + quad * 4;
#pragma unroll
        for (int g = 0; g < 4; ++g) {
          int r_g = r_base + g;
          if (r_g >= M) continue;
          float v = acc[i][j][g] + bv;
          if (RELU) v = fmaxf(v, 0.f);
          long long oidx = (long long)r_g * outLd + n_g;
          if (OBF16) ((unsigned short*)op)[oidx] = f2bf(v);
          else       ((float*)op)[oidx] = v;
        }
      }
    }
  }
}

// Fused final: out[r,n] = sum_{k<1024} bf16(p0+p1)[r,k]*w2T[n,k]
//                       + sum_{k<1024} h1b[(r+r/512)*512+k]*b2T[n,k]
//                       + rs[r]*wb2[n] + bb2[n]
// BM=BN=64, grid (64,8). Manual staging (needs the p0+p1 add), XOR-swizzled LDS.
__global__ __launch_bounds__(256) void final_gemm(
    const unsigned short* __restrict__ p0,
    const unsigned short* __restrict__ p1,
    const unsigned short* __restrict__ h1b,
    const unsigned short* __restrict__ w2T,
    const unsigned short* __restrict__ b2T,
    const float* __restrict__ rs,
    const float* __restrict__ wb2,
    const float* __restrict__ bb2,
    float* __restrict__ out)
{
  constexpr int SA = 64 * 32;
  __shared__ unsigned short smem[SA + 64 * 32];
  const int tid = threadIdx.x;
  const int lane = tid & 63, wave = tid >> 6;
  const int wm = wave >> 1, wn = wave & 1;
  const int lr = lane & 15, quad = lane >> 4;
  const int r0 = blockIdx.x * 64, n0 = blockIdx.y * 64;

  const int row = tid >> 2, seg = tid & 3;
  const int rg = r0 + row;
  const long long aG = (long long)rg * 1024 + seg * 8;
  const long long aH = ((long long)rg + (rg >> 9)) * 512 + seg * 8;
  const long long bW = (long long)(n0 + row) * 1024 + seg * 8;
  const int sAoff = row * 32 + ((seg ^ (row & 3)) * 8);
  const int sBoff = SA + row * 32 + ((seg ^ (row & 3)) * 8);

  int aoff[2], boff[2];
#pragma unroll
  for (int i = 0; i < 2; ++i) {
    int rr = wm * 32 + i * 16 + lr;
    aoff[i] = rr * 32 + ((quad ^ (rr & 3)) * 8);
    int nn = wn * 32 + i * 16 + lr;
    boff[i] = SA + nn * 32 + ((quad ^ (nn & 3)) * 8);
  }

  float4v acc[2][2];
  const float4v z4 = {0.f, 0.f, 0.f, 0.f};
  acc[0][0] = z4; acc[0][1] = z4; acc[1][0] = z4; acc[1][1] = z4;

  for (int k0 = 0; k0 < 2048; k0 += 32) {
    if (k0 < 1024) {
      short8 a0 = *(const short8*)(p0 + aG + k0);
      short8 a1 = *(const short8*)(p1 + aG + k0);
      unsigned short st[8];
#pragma unroll
      for (int j = 0; j < 8; ++j)
        st[j] = f2bf(bf2f((unsigned short)a0[j]) + bf2f((unsigned short)a1[j]));
      *(uint4*)(smem + sAoff) = *(const uint4*)(st);
      *(uint4*)(smem + sBoff) = *(const uint4*)(w2T + bW + k0);
    } else {
      *(uint4*)(smem + sAoff) = *(const uint4*)(h1b + aH + (k0 - 1024));
      *(uint4*)(smem + sBoff) = *(const uint4*)(b2T + bW + (k0 - 1024));
    }
    __syncthreads();
    short8 af[2], bfr[2];
    af[0] = *(const short8*)(smem + aoff[0]);
    af[1] = *(const short8*)(smem + aoff[1]);
    bfr[0] = *(const short8*)(smem + boff[0]);
    bfr[1] = *(const short8*)(smem + boff[1]);
#pragma unroll
    for (int i = 0; i < 2; ++i)
#pragma unroll
      for (int j = 0; j < 2; ++j)
        acc[i][j] = __builtin_amdgcn_mfma_f32_16x16x32_bf16(af[i], bfr[j], acc[i][j], 0, 0, 0);
    __syncthreads();
  }

#pragma unroll
  for (int j = 0; j < 2; ++j) {
    int n_g = n0 + wn * 32 + j * 16 + lr;
    float w2b = wb2[n_g], bbv = bb2[n_g];
#pragma unroll
    for (int i = 0; i < 2; ++i) {
      int rb = r0 + wm * 32 + i * 16 + quad * 4;
#pragma unroll
      for (int g = 0; g < 4; ++g) {
        int r_g = rb + g;
        out[(long long)r_g * 512 + n_g] = acc[i][j][g] + rs[r_g] * w2b + bbv;
      }
    }
  }
}

extern "C" void kernel_launch(void* const* d_in, const int* in_sizes, int n_in,
                              void* d_out, int out_size, void* d_ws, size_t ws_size,
                              hipStream_t stream) {
  const float* x   = (const float*)d_in[0];
  const float* z   = (const float*)d_in[1];
  const float* ww1 = (const float*)d_in[2];
  const float* wb1 = (const float*)d_in[3];
  const float* ww2 = (const float*)d_in[4];
  const float* wb2 = (const float*)d_in[5];
  const float* bw1 = (const float*)d_in[6];
  const float* bb1 = (const float*)d_in[7];
  const float* bw2 = (const float*)d_in[8];
  const float* bb2 = (const float*)d_in[9];

  char* ws = (char*)d_ws;
  unsigned short* xs  = (unsigned short*)ws; ws += 16777216ll * 2;  // (8,512,4096) shifted bf16
  unsigned short* xz  = (unsigned short*)ws; ws += 16777216ll * 2;  // (8,512,4096) t0-zeroed bf16
  unsigned short* zb  = (unsigned short*)ws; ws += 4196352ll  * 2;  // (8,4098,128) bf16; reused as p0
  unsigned short* h1T = (unsigned short*)ws; ws += 16777216ll * 2;  // (8,512,4096) h1 transposed bf16
  unsigned short* h1b = (unsigned short*)ws; ws += 2101248ll  * 2;  // (8,513,512) bias-path h1 bf16
  unsigned short* w2T = (unsigned short*)ws; ws += 524288ll * 2;    // (512,1024)
  unsigned short* b2T = (unsigned short*)ws; ws += 524288ll * 2;
  float* rs = (float*)ws;                    ws += 4096ll * 4;      // rowsum(xs)
  // REGION_X: w1T/b1T live until conv1-b, then overwritten by p1 during G
  unsigned short* w1T = (unsigned short*)ws;                        // (512,256)
  unsigned short* b1T = (unsigned short*)ws + 131072;               // (512,256)
  unsigned short* p1  = (unsigned short*)ws;                        // (4096,1024) bf16
  unsigned short* p0  = zb;                                         // (4096,1024) bf16

  prep_all<<<21512, 256, 0, stream>>>(ww1, ww2, bw1, bw2, z, w1T, w2T, b1T, b2T, zb);
  cvt_x<<<4096, 256, 0, stream>>>(x, xs, xz, rs);

  // conv1-w -> h1T (TRANS, relu): M=8*4096, K=256, A row = (r + 2b)*128
  gemm_bt<128, 128, true, true, true, false><<<dim3(256, 4), 256, 0, stream>>>(
      zb, nullptr, w1T, wb1, h1T, nullptr,
      32768, 256, 4096, 2, 128, 0, 0xFFFF, 0, 512ll * 4096, 4096);
  // conv1-b (t<513): M=8*513, A row = (r + 3585b)*128 -> h1b bf16
  gemm_bt<64, 128, true, true, false, false><<<dim3(65, 4), 256, 0, stream>>>(
      zb, nullptr, b1T, bb1, h1b, nullptr,
      4104, 256, 513, 3585, 128, 0, 0xFFFF, 0, 0, 512);
  // G = [xs ; xz] @ h1T^T, split-K x2 -> p0, p1 (bf16):
  // M=4096, N=1024, Ktot=4096, Kchunk=2048; B per-batch rows, bRowMask=511
  gemm_bt<128, 128, false, true, false, true><<<dim3(32, 8, 2), 256, 0, stream>>>(
      xs, xz, h1T, nullptr, p0, p1,
      4096, 2048, 512, 0, 4096, 512, 511, 512ll * 4096, 0, 1024);
  // out = (p0+p1) @ w2 + h1b-pair @ b2 + rs x wb2 + bb2
  final_gemm<<<dim3(64, 8), 256, 0, stream>>>(
      p0, p1, h1b, w2T, b2T, rs, wb2, bb2, (float*)d_out);
}